// Round 12
// baseline (392.470 us; speedup 1.0000x reference)
//
#include <hip/hip_runtime.h>
#include <hip/hip_bf16.h>

#define B_ 4
#define T_ 1024
#define D_ 512
#define H_ 8
#define S_ 16
#define HD_ 64
#define ITS 8    // i-rows per WG (stats)
#define ITW 8    // i-rows per WG (attnw)
#define PVI 32   // i-rows per WG (pv)
#define PVJ 64   // j-chunk (pv)

typedef short bf16x8 __attribute__((ext_vector_type(8)));
typedef float f32x4m __attribute__((ext_vector_type(4)));

__device__ __forceinline__ unsigned short f2bf(float f) {
  unsigned u = __float_as_uint(f);
  unsigned r = (u + 0x7FFFu + ((u >> 16) & 1u)) >> 16;  // RNE
  return (unsigned short)r;
}
__device__ __forceinline__ float bf2f(unsigned short h) {
  return __uint_as_float((unsigned)h << 16);
}

// ---------------- params: centers, inv_var, eff_amps, inv_temp ----------------
__global__ void k_params(const float* __restrict__ base_centers,
                         const float* __restrict__ center_deltas,
                         const float* __restrict__ log_scales,
                         const float* __restrict__ log_amps,
                         const float* __restrict__ movement_param,
                         const float* __restrict__ temperature,
                         float* __restrict__ centers,
                         float* __restrict__ inv_var,
                         float* __restrict__ eff_amps,
                         float* __restrict__ inv_temp) {
  int tid = blockIdx.x * blockDim.x + threadIdx.x;
  float move = (1.f / (1.f + __expf(-movement_param[0]))) * 0.2f;
  for (int i = tid; i < H_ * S_ * HD_; i += blockDim.x * gridDim.x)
    centers[i] = base_centers[i] + center_deltas[i] * move;
  if (tid < H_ * S_) {
    float sc = __expf(log_scales[tid]);
    sc = fminf(fmaxf(sc, 1e-4f), 5.f);
    float am = __expf(log_amps[tid]);
    am = fminf(fmaxf(am, 1e-6f), 10.f);
    inv_var[tid] = 1.f / (sc * sc + 1e-8f);
    eff_amps[tid] = (am > 0.001f) ? am : 0.f;
  }
  if (tid == 0) {
    float t = fminf(fmaxf(temperature[0], 0.01f), 10.f);
    inv_temp[0] = 1.f / t;
  }
}

// ---------------- split fp32 -> (hi, lo) bf16 pair ----------------
__global__ __launch_bounds__(256) void k_split(const float* __restrict__ src,
                                               unsigned short* __restrict__ hi,
                                               unsigned short* __restrict__ lo,
                                               int n4) {
  int i = blockIdx.x * blockDim.x + threadIdx.x;
  if (i >= n4) return;
  float4 v = ((const float4*)src)[i];
  ushort4 h, l;
  h.x = f2bf(v.x); l.x = f2bf(v.x - bf2f(h.x));
  h.y = f2bf(v.y); l.y = f2bf(v.y - bf2f(h.y));
  h.z = f2bf(v.z); l.z = f2bf(v.z - bf2f(h.z));
  h.w = f2bf(v.w); l.w = f2bf(v.w - bf2f(h.w));
  ((ushort4*)hi)[i] = h;
  ((ushort4*)lo)[i] = l;
}

// ---------------- split-bf16 MFMA GEMM: C[M,N] = A[M,K] @ Bw[N,K]^T ----------------
template <int BN>
__global__ __launch_bounds__(256) void gemm_mfma(const unsigned short* __restrict__ Ah,
                                                 const unsigned short* __restrict__ Al,
                                                 const unsigned short* __restrict__ Bh,
                                                 const unsigned short* __restrict__ Bl,
                                                 float* __restrict__ C,
                                                 int M, int N, int K) {
  constexpr int NF = BN / 16;
  const int t = threadIdx.x;
  const int lane = t & 63;
  const int wv = t >> 6;
  const int m0 = blockIdx.y * 128 + wv * 32;  // 4 waves stacked in M
  const int n0 = blockIdx.x * BN;
  const int lr = lane & 15;
  const int kg = lane >> 4;

  const unsigned short* a0h = Ah + (size_t)(m0 + lr) * K + kg * 8;
  const unsigned short* a1h = a0h + (size_t)16 * K;
  const unsigned short* a0l = Al + (size_t)(m0 + lr) * K + kg * 8;
  const unsigned short* a1l = a0l + (size_t)16 * K;
  const unsigned short* bph = Bh + (size_t)(n0 + lr) * K + kg * 8;
  const unsigned short* bpl = Bl + (size_t)(n0 + lr) * K + kg * 8;

  f32x4m acc[2][NF];
#pragma unroll
  for (int i = 0; i < 2; ++i)
#pragma unroll
    for (int f = 0; f < NF; ++f) {
      f32x4m z = {0.f, 0.f, 0.f, 0.f};
      acc[i][f] = z;
    }

  for (int k0 = 0; k0 < K; k0 += 32) {
    bf16x8 ah0 = *(const bf16x8*)(a0h + k0);
    bf16x8 ah1 = *(const bf16x8*)(a1h + k0);
    bf16x8 al0 = *(const bf16x8*)(a0l + k0);
    bf16x8 al1 = *(const bf16x8*)(a1l + k0);
#pragma unroll
    for (int f = 0; f < NF; ++f) {
      bf16x8 vbh = *(const bf16x8*)(bph + (size_t)f * 16 * K + k0);
      bf16x8 vbl = *(const bf16x8*)(bpl + (size_t)f * 16 * K + k0);
      acc[0][f] = __builtin_amdgcn_mfma_f32_16x16x32_bf16(al0, vbh, acc[0][f], 0, 0, 0);
      acc[0][f] = __builtin_amdgcn_mfma_f32_16x16x32_bf16(ah0, vbl, acc[0][f], 0, 0, 0);
      acc[0][f] = __builtin_amdgcn_mfma_f32_16x16x32_bf16(ah0, vbh, acc[0][f], 0, 0, 0);
      acc[1][f] = __builtin_amdgcn_mfma_f32_16x16x32_bf16(al1, vbh, acc[1][f], 0, 0, 0);
      acc[1][f] = __builtin_amdgcn_mfma_f32_16x16x32_bf16(ah1, vbl, acc[1][f], 0, 0, 0);
      acc[1][f] = __builtin_amdgcn_mfma_f32_16x16x32_bf16(ah1, vbh, acc[1][f], 0, 0, 0);
    }
  }
#pragma unroll
  for (int i = 0; i < 2; ++i)
#pragma unroll
    for (int f = 0; f < NF; ++f)
#pragma unroll
      for (int r = 0; r < 4; ++r)
        C[(size_t)(m0 + i * 16 + kg * 4 + r) * N + n0 + f * 16 + lr] = acc[i][f][r];
}

// ---------------- gaussian kernel weights: q_w (× 1/temp), k_w ----------------
__global__ __launch_bounds__(256) void k_gauss(const float* __restrict__ qkv,
                                               const float* __restrict__ centers,
                                               const float* __restrict__ inv_var,
                                               const float* __restrict__ eff_amps,
                                               const float* __restrict__ inv_temp,
                                               float* __restrict__ qw,
                                               float* __restrict__ kw) {
  int gid = blockIdx.x * blockDim.x + threadIdx.x;
  if (gid >= B_ * T_ * H_ * S_) return;
  int s = gid & 15;
  int h = (gid >> 4) & 7;
  int bt = gid >> 7;  // b*T + t
  const float* qrow = qkv + (size_t)bt * 1536 + h * 64;
  const float* krow = qrow + 512;
  const float* c = centers + (h * 16 + s) * 64;
  float qd = 0.f, kd = 0.f;
#pragma unroll
  for (int d = 0; d < 64; d += 4) {
    float4 cv = *(const float4*)(c + d);
    float4 qv = *(const float4*)(qrow + d);
    float4 kv = *(const float4*)(krow + d);
    float t;
    t = qv.x - cv.x; qd += t * t;
    t = qv.y - cv.y; qd += t * t;
    t = qv.z - cv.z; qd += t * t;
    t = qv.w - cv.w; qd += t * t;
    t = kv.x - cv.x; kd += t * t;
    t = kv.y - cv.y; kd += t * t;
    t = kv.z - cv.z; kd += t * t;
    t = kv.w - cv.w; kd += t * t;
  }
  qd = fminf(qd, 100.f);
  kd = fminf(kd, 100.f);
  float iv = inv_var[h * 16 + s];
  float ea = eff_amps[h * 16 + s];
  qw[gid] = __expf(-0.5f * qd * iv) * ea * inv_temp[0];
  kw[gid] = __expf(-0.5f * kd * iv) * ea;
}

// ---------------- V transpose to bf16 hi/lo panels: Vt[b][h][d][j] ----------------
// grid: B*H*16 WGs (one 64-j chunk each).
__global__ __launch_bounds__(256) void k_vtr(const float* __restrict__ qkv,
                                             unsigned short* __restrict__ vth,
                                             unsigned short* __restrict__ vtl) {
  const int bid = blockIdx.x;
  const int jc = bid & 15;
  const int h = (bid >> 4) & 7;
  const int b = bid >> 7;
  const int j0 = jc * 64;
  const int t = threadIdx.x;
  __shared__ float Vl[64][68];
  {
    int jj = t >> 2, dqg = t & 3;
    const float* vp = qkv + (size_t)(b * T_ + j0 + jj) * 1536 + 1024 + h * 64 + dqg * 16;
#pragma unroll
    for (int q = 0; q < 4; ++q) {
      float4 v = *(const float4*)(vp + q * 4);
      *(float4*)&Vl[jj][dqg * 16 + q * 4] = v;
    }
  }
  __syncthreads();
  {
    int d = t >> 2, jg = t & 3;
    ushort4 hs[4], ls[4];
#pragma unroll
    for (int q = 0; q < 4; ++q) {
      float f0 = Vl[jg * 16 + q * 4 + 0][d];
      float f1 = Vl[jg * 16 + q * 4 + 1][d];
      float f2 = Vl[jg * 16 + q * 4 + 2][d];
      float f3 = Vl[jg * 16 + q * 4 + 3][d];
      hs[q].x = f2bf(f0); ls[q].x = f2bf(f0 - bf2f(hs[q].x));
      hs[q].y = f2bf(f1); ls[q].y = f2bf(f1 - bf2f(hs[q].y));
      hs[q].z = f2bf(f2); ls[q].z = f2bf(f2 - bf2f(hs[q].z));
      hs[q].w = f2bf(f3); ls[q].w = f2bf(f3 - bf2f(hs[q].w));
    }
    size_t off = ((size_t)(b * H_ + h) * 64 + d) * 1024 + j0 + jg * 16;
#pragma unroll
    for (int q = 0; q < 4; ++q) {
      *(ushort4*)(vth + off + q * 4) = hs[q];
      *(ushort4*)(vtl + off + q * 4) = ls[q];
    }
  }
}

// ---------------- softmax stats v2: register-qw, zero-LDS hot loop ----------------
// Thread owns 2 rows (32 qw VGPRs) x its own j-column; kw read from global
// (one 64B line per lane). Merge: 4-level shfl_xor + tiny LDS cross-wave.
__global__ __launch_bounds__(256) void k_stats(const float* __restrict__ qw_g,
                                               const float* __restrict__ kw_g,
                                               float* __restrict__ m_g,
                                               float* __restrict__ is_g) {
  const int x = blockIdx.x;
  const int ic = x & 127;
  const int h = (x >> 7) & 7;
  const int b = x >> 10;
  const int i0 = ic * ITS;
  const int t = threadIdx.x;
  const int rp = t & 3;   // row-pair id
  const int jl = t >> 2;  // 0..63 j-lane

  __shared__ float red[4][4][2][2];  // [wave][rp][row-in-pair][m|s]

  float qwr[2][16], mr[2], sr[2];
#pragma unroll
  for (int e = 0; e < 2; ++e) {
    const float* qp = qw_g + (((size_t)(b * T_ + i0 + rp * 2 + e) * H_ + h) * S_);
#pragma unroll
    for (int s4 = 0; s4 < 4; ++s4) {
      float4 v = *(const float4*)(qp + s4 * 4);
      qwr[e][s4 * 4 + 0] = v.x; qwr[e][s4 * 4 + 1] = v.y;
      qwr[e][s4 * 4 + 2] = v.z; qwr[e][s4 * 4 + 3] = v.w;
    }
    mr[e] = -1e30f; sr[e] = 0.f;
  }

  for (int c = 0; c < T_ / 64; ++c) {
    int j = c * 64 + jl;
    const float* kp = kw_g + ((size_t)(b * T_ + j) * H_ + h) * S_;
    float4 k0 = *(const float4*)(kp);
    float4 k1 = *(const float4*)(kp + 4);
    float4 k2 = *(const float4*)(kp + 8);
    float4 k3 = *(const float4*)(kp + 12);
#pragma unroll
    for (int e = 0; e < 2; ++e) {
      float d = qwr[e][0] * k0.x + qwr[e][1] * k0.y + qwr[e][2] * k0.z + qwr[e][3] * k0.w +
                qwr[e][4] * k1.x + qwr[e][5] * k1.y + qwr[e][6] * k1.z + qwr[e][7] * k1.w +
                qwr[e][8] * k2.x + qwr[e][9] * k2.y + qwr[e][10] * k2.z + qwr[e][11] * k2.w +
                qwr[e][12] * k3.x + qwr[e][13] * k3.y + qwr[e][14] * k3.z + qwr[e][15] * k3.w;
      float mn = fmaxf(mr[e], d);
      sr[e] = sr[e] * __expf(mr[e] - mn) + __expf(d - mn);
      mr[e] = mn;
    }
  }
  // merge the 16 same-rp lanes within the wave (xor strides preserve t&3)
#pragma unroll
  for (int o = 4; o < 64; o <<= 1) {
#pragma unroll
    for (int e = 0; e < 2; ++e) {
      float m2 = __shfl_xor(mr[e], o);
      float s2 = __shfl_xor(sr[e], o);
      float mn = fmaxf(mr[e], m2);
      sr[e] = sr[e] * __expf(mr[e] - mn) + s2 * __expf(m2 - mn);
      mr[e] = mn;
    }
  }
  int wv = t >> 6;
  if ((t & 63) < 4) {
    red[wv][rp][0][0] = mr[0]; red[wv][rp][0][1] = sr[0];
    red[wv][rp][1][0] = mr[1]; red[wv][rp][1][1] = sr[1];
  }
  __syncthreads();
  if (t < ITS) {
    int rpp = t >> 1, e = t & 1;
    float mf = red[0][rpp][e][0], sf = red[0][rpp][e][1];
#pragma unroll
    for (int w = 1; w < 4; ++w) {
      float m2 = red[w][rpp][e][0], s2 = red[w][rpp][e][1];
      float mn = fmaxf(mf, m2);
      sf = sf * __expf(mf - mn) + s2 * __expf(m2 - mn);
      mf = mn;
    }
    size_t o = (size_t)(b * H_ + h) * T_ + i0 + t;
    m_g[o] = mf;
    is_g[o] = 1.f / sf;
  }
}

// ---------------- attn writer v2: register-qw logit phase (LDS-free) ----------------
// Thread owns (h, 2 rows, 8 j); qw/m/is in registers; kw from global.
// Tile write + coalesced transpose-gather unchanged.
__global__ __launch_bounds__(256, 4) void k_attnw(const float* __restrict__ qw_g,
                                                  const float* __restrict__ kw_g,
                                                  const float* __restrict__ m_g,
                                                  const float* __restrict__ is_g,
                                                  float* __restrict__ attn) {
  const int x = blockIdx.x;
  const int jt = x & 3;
  const int it = (x >> 2) & 127;
  const int b = x >> 9;
  const int i0 = it * ITW;
  const int jbase = jt * 256;
  const int t = threadIdx.x;

  __shared__ float tile[ITW][H_][68];  // 17.4 KB

  const int h = t >> 5;
  const int sub = t & 31;
  const int rp = sub >> 3;  // 0..3 row-pair
  const int jg = sub & 7;   // 0..7 j-group of 8

  float qwr[2][16], mr2[2], is2[2];
#pragma unroll
  for (int e = 0; e < 2; ++e) {
    const float* qp = qw_g + (((size_t)(b * T_ + i0 + rp * 2 + e) * H_ + h) * S_);
#pragma unroll
    for (int s4 = 0; s4 < 4; ++s4) {
      float4 v = *(const float4*)(qp + s4 * 4);
      qwr[e][s4 * 4 + 0] = v.x; qwr[e][s4 * 4 + 1] = v.y;
      qwr[e][s4 * 4 + 2] = v.z; qwr[e][s4 * 4 + 3] = v.w;
    }
    size_t o = (size_t)(b * H_ + h) * T_ + i0 + rp * 2 + e;
    mr2[e] = m_g[o];
    is2[e] = is_g[o];
  }

  const float* kw_b = kw_g + (size_t)b * T_ * (H_ * S_);
  float* attn_b = attn + (size_t)(b * T_ + i0) * (T_ * H_);

  for (int st = 0; st < 4; ++st) {
    const int j0 = jbase + st * 64;
    float pe[2][8];
#pragma unroll
    for (int u = 0; u < 8; ++u) {
      const float* kp = kw_b + ((size_t)(j0 + jg * 8 + u) * H_ + h) * S_;
      float4 k0 = *(const float4*)(kp);
      float4 k1 = *(const float4*)(kp + 4);
      float4 k2 = *(const float4*)(kp + 8);
      float4 k3 = *(const float4*)(kp + 12);
#pragma unroll
      for (int e = 0; e < 2; ++e) {
        float d = qwr[e][0] * k0.x + qwr[e][1] * k0.y + qwr[e][2] * k0.z + qwr[e][3] * k0.w +
                  qwr[e][4] * k1.x + qwr[e][5] * k1.y + qwr[e][6] * k1.z + qwr[e][7] * k1.w +
                  qwr[e][8] * k2.x + qwr[e][9] * k2.y + qwr[e][10] * k2.z + qwr[e][11] * k2.w +
                  qwr[e][12] * k3.x + qwr[e][13] * k3.y + qwr[e][14] * k3.z + qwr[e][15] * k3.w;
        pe[e][u] = __expf(d - mr2[e]) * is2[e];
      }
    }
#pragma unroll
    for (int e = 0; e < 2; ++e) {
      *(float4*)&tile[rp * 2 + e][h][jg * 8] =
          make_float4(pe[e][0], pe[e][1], pe[e][2], pe[e][3]);
      *(float4*)&tile[rp * 2 + e][h][jg * 8 + 4] =
          make_float4(pe[e][4], pe[e][5], pe[e][6], pe[e][7]);
    }
    __syncthreads();
    // coalesced attn write: per r, 64 j x 8 h = 512 contiguous floats
#pragma unroll
    for (int l = 0; l < 4; ++l) {
      int f = (l * 256 + t) * 4;
      int r = f >> 9;
      int rem = f & 511;
      int jl = rem >> 3;
      int h0 = rem & 7;  // 0 or 4
      float4 v;
      v.x = tile[r][h0 + 0][jl];
      v.y = tile[r][h0 + 1][jl];
      v.z = tile[r][h0 + 2][jl];
      v.w = tile[r][h0 + 3][jl];
      *(float4*)(attn_b + (size_t)r * (T_ * H_) + (size_t)(j0 + jl) * H_ + h0) = v;
    }
    __syncthreads();
  }
}

// ---------------- PV via MFMA, V from transposed bf16 panels (v5) ----------------
// Phase 1: per-lane P A-frag in registers (VALU logits from swizzled kw LDS),
// scalar hi/lo split (no asm cvt_pk — m240). Phase 2: B-frags loaded DIRECTLY
// from global Vt panels as bf16x8 (L2-resident per XCD) — zero V LDS, zero
// per-chunk split work. LDS: kw 4KB + merge scratch 8.7KB.
__global__ __launch_bounds__(256, 4) void k_pv(const float* __restrict__ qw_g,
                                               const float* __restrict__ kw_g,
                                               const float* __restrict__ m_g,
                                               const float* __restrict__ is_g,
                                               const unsigned short* __restrict__ vth,
                                               const unsigned short* __restrict__ vtl,
                                               unsigned short* __restrict__ oph,
                                               unsigned short* __restrict__ opl) {
  const int bid = blockIdx.x;
  const int xcd = bid & 7;
  const int qq = bid >> 3;             // 0..127
  const int p = xcd * 4 + (qq & 3);    // panel 0..31
  const int ib = qq >> 2;              // 0..31
  const int b = p >> 3;
  const int h = p & 7;
  const int i0 = ib * PVI;
  const int t = threadIdx.x;
  const int lane = t & 63;
  const int w = t >> 6;
  const int I = w >> 1;                // i-frag
  const int S = w & 1;                 // k-step (32-j half of chunk)
  const int lr = lane & 15;
  const int kg = lane >> 4;

  __shared__ float kw_sw[PVJ][16];     // 4 KB; s4-block ^= (j>>3)&3
  __shared__ float mgs[128][17];       // 8.7 KB merge scratch

  // per-lane invariants: qw row, m, 1/s (asm-pinned against remat)
  const int irow = I * 16 + lr;
  float qwr[16];
  {
    const float* qp = qw_g + (((size_t)(b * T_ + i0 + irow) * H_ + h) * S_);
#pragma unroll
    for (int s4 = 0; s4 < 4; ++s4) {
      float4 v = *(const float4*)(qp + s4 * 4);
      qwr[s4 * 4 + 0] = v.x; qwr[s4 * 4 + 1] = v.y;
      qwr[s4 * 4 + 2] = v.z; qwr[s4 * 4 + 3] = v.w;
    }
  }
  float mr = m_g[(size_t)(b * H_ + h) * T_ + i0 + irow];
  float isr = is_g[(size_t)(b * H_ + h) * T_ + i0 + irow];
#pragma unroll
  for (int s = 0; s < 16; ++s) asm volatile("" : "+v"(qwr[s]));
  asm volatile("" : "+v"(mr));
  asm volatile("" : "+v"(isr));

  const unsigned short* vhp = vth + ((size_t)(b * H_ + h) * 64) * 1024;
  const unsigned short* vlp = vtl + ((size_t)(b * H_ + h) * 64) * 1024;

  f32x4m acc[4];
#pragma unroll
  for (int f = 0; f < 4; ++f) { f32x4m z = {0.f, 0.f, 0.f, 0.f}; acc[f] = z; }

  for (int jc = 0; jc < T_ / PVJ; ++jc) {
    const int j0 = jc * PVJ;
    __syncthreads();  // prior chunk's kw readers done
    {
      int j = t >> 2, s4g = t & 3;
      float4 v = *(const float4*)(kw_g + (((size_t)(b * T_ + j0 + j) * H_ + h) * S_ + s4g * 4));
      int blk = s4g ^ ((j >> 3) & 3);
      *(float4*)&kw_sw[j][blk * 4] = v;
    }
    __syncthreads();
    // ---- phase 1: logits -> P A-frag (hi/lo bf16) in registers ----
    union UA { unsigned short s[8]; bf16x8 v; } AH, AL;
#pragma unroll
    for (int u = 0; u < 8; ++u) {
      int jr = S * 32 + kg * 8 + u;    // chunk-local j
      int g = (jr >> 3) & 3;
      float d = 0.f;
#pragma unroll
      for (int s4 = 0; s4 < 4; ++s4) {
        float4 kv = *(const float4*)&kw_sw[jr][(s4 ^ g) * 4];
        d += qwr[s4 * 4 + 0] * kv.x + qwr[s4 * 4 + 1] * kv.y +
             qwr[s4 * 4 + 2] * kv.z + qwr[s4 * 4 + 3] * kv.w;
      }
      float pv = __expf(d - mr) * isr;
      unsigned short hh = f2bf(pv);
      AH.s[u] = hh;
      AL.s[u] = f2bf(pv - bf2f(hh));
    }
    // ---- phase 2: B-frags straight from global Vt (bf16x8), 3 MFMA each ----
#pragma unroll
    for (int f = 0; f < 4; ++f) {
      size_t voff = (size_t)(f * 16 + lr) * 1024 + j0 + S * 32 + kg * 8;
      bf16x8 BHv = *(const bf16x8*)(vhp + voff);
      bf16x8 BLv = *(const bf16x8*)(vlp + voff);
      acc[f] = __builtin_amdgcn_mfma_f32_16x16x32_bf16(AL.v, BHv, acc[f], 0, 0, 0);
      acc[f] = __builtin_amdgcn_mfma_f32_16x16x32_bf16(AH.v, BLv, acc[f], 0, 0, 0);
      acc[f] = __builtin_amdgcn_mfma_f32_16x16x32_bf16(AH.v, BHv, acc[f], 0, 0, 0);
    }
  }
  // ---- merge S=0 + S=1 partials, convert, store bf16 hi/lo ----
  __syncthreads();
  if (S == 1) {
    float* dst = &mgs[I * 64 + lane][0];
#pragma unroll
    for (int f = 0; f < 4; ++f)
#pragma unroll
      for (int r = 0; r < 4; ++r) dst[f * 4 + r] = acc[f][r];
  }
  __syncthreads();
  if (S == 0) {
    const float* src = &mgs[I * 64 + lane][0];
#pragma unroll
    for (int f = 0; f < 4; ++f) {
#pragma unroll
      for (int r = 0; r < 4; ++r) {
        float o = acc[f][r] + src[f * 4 + r];
        unsigned short hh = f2bf(o);
        unsigned short ll = f2bf(o - bf2f(hh));
        size_t idx = (size_t)(b * T_ + i0 + I * 16 + kg * 4 + r) * D_ + h * HD_ + f * 16 + lr;
        oph[idx] = hh;
        opl[idx] = ll;
      }
    }
  }
}

extern "C" void kernel_launch(void* const* d_in, const int* in_sizes, int n_in,
                              void* d_out, int out_size, void* d_ws, size_t ws_size,
                              hipStream_t stream) {
  const float* x = (const float*)d_in[0];
  const float* qkv_w = (const float*)d_in[1];
  const float* out_w = (const float*)d_in[2];
  const float* base_c = (const float*)d_in[3];
  const float* deltas = (const float*)d_in[4];
  const float* log_sc = (const float*)d_in[5];
  const float* log_am = (const float*)d_in[6];
  const float* move_p = (const float*)d_in[7];
  const float* temp = (const float*)d_in[8];

  float* out = (float*)d_out;                    // B*T*D
  float* attn = out + (size_t)B_ * T_ * D_;      // B*T*T*H

  float* ws = (float*)d_ws;
  float* qkv = ws;                                          // 6,291,456 f
  float* qw = qkv + 6291456;                                // 524,288
  float* kw = qw + 524288;                                  // 524,288
  float* centers = kw + 524288;                             // 8,192
  float* inv_var = centers + 8192;                          // 128
  float* eff_amps = inv_var + 128;                          // 128
  float* inv_temp = eff_amps + 128;                         // 4
  float* m_g = inv_temp + 4;                                // 32,768
  float* is_g = m_g + 32768;                                // 32,768
  unsigned short* xh = (unsigned short*)(is_g + 32768);     // 2,097,152 us
  unsigned short* xl = xh + 2097152;                        // 2,097,152
  unsigned short* wh = xl + 2097152;                        // 786,432
  unsigned short* wl = wh + 786432;                         // 786,432
  unsigned short* owh = wl + 786432;                        // 262,144
  unsigned short* owl = owh + 262144;                       // 262,144
  unsigned short* oph = owl + 262144;                       // 2,097,152
  unsigned short* opl = oph + 2097152;                      // 2,097,152
  unsigned short* vth = opl + 2097152;                      // 2,097,152
  unsigned short* vtl = vth + 2097152;                      // 2,097,152

  k_params<<<32, 256, 0, stream>>>(base_c, deltas, log_sc, log_am, move_p, temp,
                                   centers, inv_var, eff_amps, inv_temp);
  k_split<<<2048, 256, 0, stream>>>(x, xh, xl, 2097152 / 4);
  k_split<<<768, 256, 0, stream>>>(qkv_w, wh, wl, 786432 / 4);
  k_split<<<256, 256, 0, stream>>>(out_w, owh, owl, 262144 / 4);

  dim3 g1(1536 / 64, 4096 / 128);   // 24 x 32 = 768 WGs
  gemm_mfma<64><<<g1, 256, 0, stream>>>(xh, xl, wh, wl, qkv, B_ * T_, 3 * D_, D_);

  k_gauss<<<(B_ * T_ * H_ * S_) / 256, 256, 0, stream>>>(qkv, centers, inv_var,
                                                         eff_amps, inv_temp, qw, kw);
  k_vtr<<<B_ * H_ * 16, 256, 0, stream>>>(qkv, vth, vtl);
  k_stats<<<B_ * H_ * (T_ / ITS), 256, 0, stream>>>(qw, kw, m_g, is_g);
  k_attnw<<<B_ * (T_ / ITW) * 4, 256, 0, stream>>>(qw, kw, m_g, is_g, attn);
  k_pv<<<B_ * H_ * (T_ / PVI), 256, 0, stream>>>(qw, kw, m_g, is_g, vth, vtl, oph, opl);

  dim3 g2(512 / 64, 4096 / 128);    // 8 x 32 = 256 WGs
  gemm_mfma<64><<<g2, 256, 0, stream>>>(oph, opl, owh, owl, out, B_ * T_, D_, D_);
}

// Round 13
// 315.528 us; speedup vs baseline: 1.2439x; 1.2439x over previous
//
#include <hip/hip_runtime.h>
#include <hip/hip_bf16.h>

#define B_ 4
#define T_ 1024
#define D_ 512
#define H_ 8
#define S_ 16
#define HD_ 64
#define ITS 8    // i-rows per WG (stats)
#define ITW 8    // i-rows per WG (attnw)
#define PVI 32   // i-rows per WG (pv)
#define PVJ 64   // j-chunk (pv)

typedef short bf16x8 __attribute__((ext_vector_type(8)));
typedef float f32x4m __attribute__((ext_vector_type(4)));

__device__ __forceinline__ unsigned short f2bf(float f) {
  unsigned u = __float_as_uint(f);
  unsigned r = (u + 0x7FFFu + ((u >> 16) & 1u)) >> 16;  // RNE
  return (unsigned short)r;
}
__device__ __forceinline__ float bf2f(unsigned short h) {
  return __uint_as_float((unsigned)h << 16);
}

// ---------------- params: centers, inv_var, eff_amps, inv_temp ----------------
__global__ void k_params(const float* __restrict__ base_centers,
                         const float* __restrict__ center_deltas,
                         const float* __restrict__ log_scales,
                         const float* __restrict__ log_amps,
                         const float* __restrict__ movement_param,
                         const float* __restrict__ temperature,
                         float* __restrict__ centers,
                         float* __restrict__ inv_var,
                         float* __restrict__ eff_amps,
                         float* __restrict__ inv_temp) {
  int tid = blockIdx.x * blockDim.x + threadIdx.x;
  float move = (1.f / (1.f + __expf(-movement_param[0]))) * 0.2f;
  for (int i = tid; i < H_ * S_ * HD_; i += blockDim.x * gridDim.x)
    centers[i] = base_centers[i] + center_deltas[i] * move;
  if (tid < H_ * S_) {
    float sc = __expf(log_scales[tid]);
    sc = fminf(fmaxf(sc, 1e-4f), 5.f);
    float am = __expf(log_amps[tid]);
    am = fminf(fmaxf(am, 1e-6f), 10.f);
    inv_var[tid] = 1.f / (sc * sc + 1e-8f);
    eff_amps[tid] = (am > 0.001f) ? am : 0.f;
  }
  if (tid == 0) {
    float t = fminf(fmaxf(temperature[0], 0.01f), 10.f);
    inv_temp[0] = 1.f / t;
  }
}

// ---------------- split fp32 -> (hi, lo) bf16 pair ----------------
__global__ __launch_bounds__(256) void k_split(const float* __restrict__ src,
                                               unsigned short* __restrict__ hi,
                                               unsigned short* __restrict__ lo,
                                               int n4) {
  int i = blockIdx.x * blockDim.x + threadIdx.x;
  if (i >= n4) return;
  float4 v = ((const float4*)src)[i];
  ushort4 h, l;
  h.x = f2bf(v.x); l.x = f2bf(v.x - bf2f(h.x));
  h.y = f2bf(v.y); l.y = f2bf(v.y - bf2f(h.y));
  h.z = f2bf(v.z); l.z = f2bf(v.z - bf2f(h.z));
  h.w = f2bf(v.w); l.w = f2bf(v.w - bf2f(h.w));
  ((ushort4*)hi)[i] = h;
  ((ushort4*)lo)[i] = l;
}

// ---------------- split-bf16 MFMA GEMM: C[M,N] = A[M,K] @ Bw[N,K]^T ----------------
template <int BN>
__global__ __launch_bounds__(256) void gemm_mfma(const unsigned short* __restrict__ Ah,
                                                 const unsigned short* __restrict__ Al,
                                                 const unsigned short* __restrict__ Bh,
                                                 const unsigned short* __restrict__ Bl,
                                                 float* __restrict__ C,
                                                 int M, int N, int K) {
  constexpr int NF = BN / 16;
  const int t = threadIdx.x;
  const int lane = t & 63;
  const int wv = t >> 6;
  const int m0 = blockIdx.y * 128 + wv * 32;  // 4 waves stacked in M
  const int n0 = blockIdx.x * BN;
  const int lr = lane & 15;
  const int kg = lane >> 4;

  const unsigned short* a0h = Ah + (size_t)(m0 + lr) * K + kg * 8;
  const unsigned short* a1h = a0h + (size_t)16 * K;
  const unsigned short* a0l = Al + (size_t)(m0 + lr) * K + kg * 8;
  const unsigned short* a1l = a0l + (size_t)16 * K;
  const unsigned short* bph = Bh + (size_t)(n0 + lr) * K + kg * 8;
  const unsigned short* bpl = Bl + (size_t)(n0 + lr) * K + kg * 8;

  f32x4m acc[2][NF];
#pragma unroll
  for (int i = 0; i < 2; ++i)
#pragma unroll
    for (int f = 0; f < NF; ++f) {
      f32x4m z = {0.f, 0.f, 0.f, 0.f};
      acc[i][f] = z;
    }

  for (int k0 = 0; k0 < K; k0 += 32) {
    bf16x8 ah0 = *(const bf16x8*)(a0h + k0);
    bf16x8 ah1 = *(const bf16x8*)(a1h + k0);
    bf16x8 al0 = *(const bf16x8*)(a0l + k0);
    bf16x8 al1 = *(const bf16x8*)(a1l + k0);
#pragma unroll
    for (int f = 0; f < NF; ++f) {
      bf16x8 vbh = *(const bf16x8*)(bph + (size_t)f * 16 * K + k0);
      bf16x8 vbl = *(const bf16x8*)(bpl + (size_t)f * 16 * K + k0);
      acc[0][f] = __builtin_amdgcn_mfma_f32_16x16x32_bf16(al0, vbh, acc[0][f], 0, 0, 0);
      acc[0][f] = __builtin_amdgcn_mfma_f32_16x16x32_bf16(ah0, vbl, acc[0][f], 0, 0, 0);
      acc[0][f] = __builtin_amdgcn_mfma_f32_16x16x32_bf16(ah0, vbh, acc[0][f], 0, 0, 0);
      acc[1][f] = __builtin_amdgcn_mfma_f32_16x16x32_bf16(al1, vbh, acc[1][f], 0, 0, 0);
      acc[1][f] = __builtin_amdgcn_mfma_f32_16x16x32_bf16(ah1, vbl, acc[1][f], 0, 0, 0);
      acc[1][f] = __builtin_amdgcn_mfma_f32_16x16x32_bf16(ah1, vbh, acc[1][f], 0, 0, 0);
    }
  }
#pragma unroll
  for (int i = 0; i < 2; ++i)
#pragma unroll
    for (int f = 0; f < NF; ++f)
#pragma unroll
      for (int r = 0; r < 4; ++r)
        C[(size_t)(m0 + i * 16 + kg * 4 + r) * N + n0 + f * 16 + lr] = acc[i][f][r];
}

// ---------------- gaussian kernel weights: q_w (× 1/temp), k_w ----------------
__global__ __launch_bounds__(256) void k_gauss(const float* __restrict__ qkv,
                                               const float* __restrict__ centers,
                                               const float* __restrict__ inv_var,
                                               const float* __restrict__ eff_amps,
                                               const float* __restrict__ inv_temp,
                                               float* __restrict__ qw,
                                               float* __restrict__ kw) {
  int gid = blockIdx.x * blockDim.x + threadIdx.x;
  if (gid >= B_ * T_ * H_ * S_) return;
  int s = gid & 15;
  int h = (gid >> 4) & 7;
  int bt = gid >> 7;  // b*T + t
  const float* qrow = qkv + (size_t)bt * 1536 + h * 64;
  const float* krow = qrow + 512;
  const float* c = centers + (h * 16 + s) * 64;
  float qd = 0.f, kd = 0.f;
#pragma unroll
  for (int d = 0; d < 64; d += 4) {
    float4 cv = *(const float4*)(c + d);
    float4 qv = *(const float4*)(qrow + d);
    float4 kv = *(const float4*)(krow + d);
    float t;
    t = qv.x - cv.x; qd += t * t;
    t = qv.y - cv.y; qd += t * t;
    t = qv.z - cv.z; qd += t * t;
    t = qv.w - cv.w; qd += t * t;
    t = kv.x - cv.x; kd += t * t;
    t = kv.y - cv.y; kd += t * t;
    t = kv.z - cv.z; kd += t * t;
    t = kv.w - cv.w; kd += t * t;
  }
  qd = fminf(qd, 100.f);
  kd = fminf(kd, 100.f);
  float iv = inv_var[h * 16 + s];
  float ea = eff_amps[h * 16 + s];
  qw[gid] = __expf(-0.5f * qd * iv) * ea * inv_temp[0];
  kw[gid] = __expf(-0.5f * kd * iv) * ea;
}

__device__ __forceinline__ float dot16(const float4 q[4], const float4 k[4]) {
  return q[0].x * k[0].x + q[0].y * k[0].y + q[0].z * k[0].z + q[0].w * k[0].w +
         q[1].x * k[1].x + q[1].y * k[1].y + q[1].z * k[1].z + q[1].w * k[1].w +
         q[2].x * k[2].x + q[2].y * k[2].y + q[2].z * k[2].z + q[2].w * k[2].w +
         q[3].x * k[3].x + q[3].y * k[3].y + q[3].z * k[3].z + q[3].w * k[3].w;
}

// ---------------- V transpose to bf16 hi/lo panels: Vt[b][h][d][j] ----------------
__global__ __launch_bounds__(256) void k_vtr(const float* __restrict__ qkv,
                                             unsigned short* __restrict__ vth,
                                             unsigned short* __restrict__ vtl) {
  const int bid = blockIdx.x;
  const int jc = bid & 15;
  const int h = (bid >> 4) & 7;
  const int b = bid >> 7;
  const int j0 = jc * 64;
  const int t = threadIdx.x;
  __shared__ float Vl[64][68];
  {
    int jj = t >> 2, dqg = t & 3;
    const float* vp = qkv + (size_t)(b * T_ + j0 + jj) * 1536 + 1024 + h * 64 + dqg * 16;
#pragma unroll
    for (int q = 0; q < 4; ++q) {
      float4 v = *(const float4*)(vp + q * 4);
      *(float4*)&Vl[jj][dqg * 16 + q * 4] = v;
    }
  }
  __syncthreads();
  {
    int d = t >> 2, jg = t & 3;
    ushort4 hs[4], ls[4];
#pragma unroll
    for (int q = 0; q < 4; ++q) {
      float f0 = Vl[jg * 16 + q * 4 + 0][d];
      float f1 = Vl[jg * 16 + q * 4 + 1][d];
      float f2 = Vl[jg * 16 + q * 4 + 2][d];
      float f3 = Vl[jg * 16 + q * 4 + 3][d];
      hs[q].x = f2bf(f0); ls[q].x = f2bf(f0 - bf2f(hs[q].x));
      hs[q].y = f2bf(f1); ls[q].y = f2bf(f1 - bf2f(hs[q].y));
      hs[q].z = f2bf(f2); ls[q].z = f2bf(f2 - bf2f(hs[q].z));
      hs[q].w = f2bf(f3); ls[q].w = f2bf(f3 - bf2f(hs[q].w));
    }
    size_t off = ((size_t)(b * H_ + h) * 64 + d) * 1024 + j0 + jg * 16;
#pragma unroll
    for (int q = 0; q < 4; ++q) {
      *(ushort4*)(vth + off + q * 4) = hs[q];
      *(ushort4*)(vtl + off + q * 4) = ls[q];
    }
  }
}

// ---------------- softmax stats v2: register-qw, zero-LDS hot loop ----------------
__global__ __launch_bounds__(256) void k_stats(const float* __restrict__ qw_g,
                                               const float* __restrict__ kw_g,
                                               float* __restrict__ m_g,
                                               float* __restrict__ is_g) {
  const int x = blockIdx.x;
  const int ic = x & 127;
  const int h = (x >> 7) & 7;
  const int b = x >> 10;
  const int i0 = ic * ITS;
  const int t = threadIdx.x;
  const int rp = t & 3;   // row-pair id
  const int jl = t >> 2;  // 0..63 j-lane

  __shared__ float red[4][4][2][2];  // [wave][rp][row-in-pair][m|s]

  float qwr[2][16], mr[2], sr[2];
#pragma unroll
  for (int e = 0; e < 2; ++e) {
    const float* qp = qw_g + (((size_t)(b * T_ + i0 + rp * 2 + e) * H_ + h) * S_);
#pragma unroll
    for (int s4 = 0; s4 < 4; ++s4) {
      float4 v = *(const float4*)(qp + s4 * 4);
      qwr[e][s4 * 4 + 0] = v.x; qwr[e][s4 * 4 + 1] = v.y;
      qwr[e][s4 * 4 + 2] = v.z; qwr[e][s4 * 4 + 3] = v.w;
    }
    mr[e] = -1e30f; sr[e] = 0.f;
  }

  for (int c = 0; c < T_ / 64; ++c) {
    int j = c * 64 + jl;
    const float* kp = kw_g + ((size_t)(b * T_ + j) * H_ + h) * S_;
    float4 k0 = *(const float4*)(kp);
    float4 k1 = *(const float4*)(kp + 4);
    float4 k2 = *(const float4*)(kp + 8);
    float4 k3 = *(const float4*)(kp + 12);
#pragma unroll
    for (int e = 0; e < 2; ++e) {
      float d = qwr[e][0] * k0.x + qwr[e][1] * k0.y + qwr[e][2] * k0.z + qwr[e][3] * k0.w +
                qwr[e][4] * k1.x + qwr[e][5] * k1.y + qwr[e][6] * k1.z + qwr[e][7] * k1.w +
                qwr[e][8] * k2.x + qwr[e][9] * k2.y + qwr[e][10] * k2.z + qwr[e][11] * k2.w +
                qwr[e][12] * k3.x + qwr[e][13] * k3.y + qwr[e][14] * k3.z + qwr[e][15] * k3.w;
      float mn = fmaxf(mr[e], d);
      sr[e] = sr[e] * __expf(mr[e] - mn) + __expf(d - mn);
      mr[e] = mn;
    }
  }
  // merge the 16 same-rp lanes within the wave (xor strides preserve t&3)
#pragma unroll
  for (int o = 4; o < 64; o <<= 1) {
#pragma unroll
    for (int e = 0; e < 2; ++e) {
      float m2 = __shfl_xor(mr[e], o);
      float s2 = __shfl_xor(sr[e], o);
      float mn = fmaxf(mr[e], m2);
      sr[e] = sr[e] * __expf(mr[e] - mn) + s2 * __expf(m2 - mn);
      mr[e] = mn;
    }
  }
  int wv = t >> 6;
  if ((t & 63) < 4) {
    red[wv][rp][0][0] = mr[0]; red[wv][rp][0][1] = sr[0];
    red[wv][rp][1][0] = mr[1]; red[wv][rp][1][1] = sr[1];
  }
  __syncthreads();
  if (t < ITS) {
    int rpp = t >> 1, e = t & 1;
    float mf = red[0][rpp][e][0], sf = red[0][rpp][e][1];
#pragma unroll
    for (int w = 1; w < 4; ++w) {
      float m2 = red[w][rpp][e][0], s2 = red[w][rpp][e][1];
      float mn = fmaxf(mf, m2);
      sf = sf * __expf(mf - mn) + s2 * __expf(m2 - mn);
      mf = mn;
    }
    size_t o = (size_t)(b * H_ + h) * T_ + i0 + t;
    m_g[o] = mf;
    is_g[o] = 1.f / sf;
  }
}

// ---------------- attn writer (v1 revert): LDS qw + per-thread 2-j kw regs ----------------
// Round-12's register-qw variant was 4x-redundant on kw gathers + 8-way
// bank-conflicted tile writes (126us, 1.05M conflicts). This v1 form: kw
// subtile read ONCE (no redundancy), float2 tile writes (2-way = free).
__global__ __launch_bounds__(256, 4) void k_attnw(const float* __restrict__ qw_g,
                                                  const float* __restrict__ kw_g,
                                                  const float* __restrict__ m_g,
                                                  const float* __restrict__ is_g,
                                                  float* __restrict__ attn) {
  const int x = blockIdx.x;
  const int jt = x & 3;
  const int it = (x >> 2) & 127;
  const int b = x >> 9;
  const int i0 = it * ITW;
  const int jbase = jt * 256;
  const int tid = threadIdx.x;

  __shared__ float qw_l[ITW][H_ * S_];     // 4 KB
  __shared__ float msl[ITW][H_];
  __shared__ float isl[ITW][H_];
  __shared__ float tile[ITW][H_][68];      // 17.4 KB

  {
    int f = tid * 4;
    int r = f >> 7, c = f & 127;
    *(float4*)&qw_l[r][c] = *(const float4*)(qw_g + ((size_t)(b * T_ + i0 + r) * 128 + c));
  }
  if (tid < 64) {
    int r = tid >> 3, hh = tid & 7;
    size_t o = (size_t)(b * H_ + hh) * T_ + i0 + r;
    msl[r][hh] = m_g[o];
    isl[r][hh] = is_g[o];
  }
  __syncthreads();

  const int h = tid >> 5;
  const int jq = tid & 31;
  const float* kw_b = kw_g + (size_t)b * T_ * (H_ * S_);
  float* attn_b = attn + (size_t)(b * T_ + i0) * (T_ * H_);

  for (int st = 0; st < 4; ++st) {
    const int j0 = jbase + st * 64;
    const float* kp = kw_b + ((size_t)(j0 + jq * 2) * H_ + h) * S_;
    float4 ka[4], kb[4];
    ka[0] = *(const float4*)(kp);       ka[1] = *(const float4*)(kp + 4);
    ka[2] = *(const float4*)(kp + 8);   ka[3] = *(const float4*)(kp + 12);
    kb[0] = *(const float4*)(kp + 128); kb[1] = *(const float4*)(kp + 132);
    kb[2] = *(const float4*)(kp + 136); kb[3] = *(const float4*)(kp + 140);
#pragma unroll
    for (int r = 0; r < ITW; ++r) {
      float4 q4[4];
      q4[0] = *(const float4*)&qw_l[r][h * 16 + 0];
      q4[1] = *(const float4*)&qw_l[r][h * 16 + 4];
      q4[2] = *(const float4*)&qw_l[r][h * 16 + 8];
      q4[3] = *(const float4*)&qw_l[r][h * 16 + 12];
      float la = dot16(q4, ka);
      float lb = dot16(q4, kb);
      float mm = msl[r][h], ii = isl[r][h];
      *(float2*)&tile[r][h][jq * 2] =
          make_float2(__expf(la - mm) * ii, __expf(lb - mm) * ii);
    }
    __syncthreads();
#pragma unroll
    for (int l = 0; l < 4; ++l) {
      int f = (l * 256 + tid) * 4;
      int r = f >> 9;
      int rem = f & 511;
      int jl = rem >> 3;
      int h0 = rem & 7;  // 0 or 4
      float4 v;
      v.x = tile[r][h0 + 0][jl];
      v.y = tile[r][h0 + 1][jl];
      v.z = tile[r][h0 + 2][jl];
      v.w = tile[r][h0 + 3][jl];
      *(float4*)(attn_b + (size_t)r * (T_ * H_) + (size_t)(j0 + jl) * H_ + h0) = v;
    }
    __syncthreads();
  }
}

// ---------------- PV via MFMA, V from transposed bf16 panels (v5) ----------------
__global__ __launch_bounds__(256, 4) void k_pv(const float* __restrict__ qw_g,
                                               const float* __restrict__ kw_g,
                                               const float* __restrict__ m_g,
                                               const float* __restrict__ is_g,
                                               const unsigned short* __restrict__ vth,
                                               const unsigned short* __restrict__ vtl,
                                               unsigned short* __restrict__ oph,
                                               unsigned short* __restrict__ opl) {
  const int bid = blockIdx.x;
  const int xcd = bid & 7;
  const int qq = bid >> 3;             // 0..127
  const int p = xcd * 4 + (qq & 3);    // panel 0..31
  const int ib = qq >> 2;              // 0..31
  const int b = p >> 3;
  const int h = p & 7;
  const int i0 = ib * PVI;
  const int t = threadIdx.x;
  const int lane = t & 63;
  const int w = t >> 6;
  const int I = w >> 1;                // i-frag
  const int S = w & 1;                 // k-step (32-j half of chunk)
  const int lr = lane & 15;
  const int kg = lane >> 4;

  __shared__ float kw_sw[PVJ][16];     // 4 KB; s4-block ^= (j>>3)&3
  __shared__ float mgs[128][17];       // 8.7 KB merge scratch

  // per-lane invariants: qw row, m, 1/s (asm-pinned against remat)
  const int irow = I * 16 + lr;
  float qwr[16];
  {
    const float* qp = qw_g + (((size_t)(b * T_ + i0 + irow) * H_ + h) * S_);
#pragma unroll
    for (int s4 = 0; s4 < 4; ++s4) {
      float4 v = *(const float4*)(qp + s4 * 4);
      qwr[s4 * 4 + 0] = v.x; qwr[s4 * 4 + 1] = v.y;
      qwr[s4 * 4 + 2] = v.z; qwr[s4 * 4 + 3] = v.w;
    }
  }
  float mr = m_g[(size_t)(b * H_ + h) * T_ + i0 + irow];
  float isr = is_g[(size_t)(b * H_ + h) * T_ + i0 + irow];
#pragma unroll
  for (int s = 0; s < 16; ++s) asm volatile("" : "+v"(qwr[s]));
  asm volatile("" : "+v"(mr));
  asm volatile("" : "+v"(isr));

  const unsigned short* vhp = vth + ((size_t)(b * H_ + h) * 64) * 1024;
  const unsigned short* vlp = vtl + ((size_t)(b * H_ + h) * 64) * 1024;

  f32x4m acc[4];
#pragma unroll
  for (int f = 0; f < 4; ++f) { f32x4m z = {0.f, 0.f, 0.f, 0.f}; acc[f] = z; }

  for (int jc = 0; jc < T_ / PVJ; ++jc) {
    const int j0 = jc * PVJ;
    __syncthreads();  // prior chunk's kw readers done
    {
      int j = t >> 2, s4g = t & 3;
      float4 v = *(const float4*)(kw_g + (((size_t)(b * T_ + j0 + j) * H_ + h) * S_ + s4g * 4));
      int blk = s4g ^ ((j >> 3) & 3);
      *(float4*)&kw_sw[j][blk * 4] = v;
    }
    __syncthreads();
    // ---- phase 1: logits -> P A-frag (hi/lo bf16) in registers ----
    union UA { unsigned short s[8]; bf16x8 v; } AH, AL;
#pragma unroll
    for (int u = 0; u < 8; ++u) {
      int jr = S * 32 + kg * 8 + u;    // chunk-local j
      int g = (jr >> 3) & 3;
      float d = 0.f;
#pragma unroll
      for (int s4 = 0; s4 < 4; ++s4) {
        float4 kv = *(const float4*)&kw_sw[jr][(s4 ^ g) * 4];
        d += qwr[s4 * 4 + 0] * kv.x + qwr[s4 * 4 + 1] * kv.y +
             qwr[s4 * 4 + 2] * kv.z + qwr[s4 * 4 + 3] * kv.w;
      }
      float pv = __expf(d - mr) * isr;
      unsigned short hh = f2bf(pv);
      AH.s[u] = hh;
      AL.s[u] = f2bf(pv - bf2f(hh));
    }
    // ---- phase 2: B-frags straight from global Vt (bf16x8), 3 MFMA each ----
#pragma unroll
    for (int f = 0; f < 4; ++f) {
      size_t voff = (size_t)(f * 16 + lr) * 1024 + j0 + S * 32 + kg * 8;
      bf16x8 BHv = *(const bf16x8*)(vhp + voff);
      bf16x8 BLv = *(const bf16x8*)(vlp + voff);
      acc[f] = __builtin_amdgcn_mfma_f32_16x16x32_bf16(AL.v, BHv, acc[f], 0, 0, 0);
      acc[f] = __builtin_amdgcn_mfma_f32_16x16x32_bf16(AH.v, BLv, acc[f], 0, 0, 0);
      acc[f] = __builtin_amdgcn_mfma_f32_16x16x32_bf16(AH.v, BHv, acc[f], 0, 0, 0);
    }
  }
  // ---- merge S=0 + S=1 partials, convert, store bf16 hi/lo ----
  __syncthreads();
  if (S == 1) {
    float* dst = &mgs[I * 64 + lane][0];
#pragma unroll
    for (int f = 0; f < 4; ++f)
#pragma unroll
      for (int r = 0; r < 4; ++r) dst[f * 4 + r] = acc[f][r];
  }
  __syncthreads();
  if (S == 0) {
    const float* src = &mgs[I * 64 + lane][0];
#pragma unroll
    for (int f = 0; f < 4; ++f) {
#pragma unroll
      for (int r = 0; r < 4; ++r) {
        float o = acc[f][r] + src[f * 4 + r];
        unsigned short hh = f2bf(o);
        unsigned short ll = f2bf(o - bf2f(hh));
        size_t idx = (size_t)(b * T_ + i0 + I * 16 + kg * 4 + r) * D_ + h * HD_ + f * 16 + lr;
        oph[idx] = hh;
        opl[idx] = ll;
      }
    }
  }
}

extern "C" void kernel_launch(void* const* d_in, const int* in_sizes, int n_in,
                              void* d_out, int out_size, void* d_ws, size_t ws_size,
                              hipStream_t stream) {
  const float* x = (const float*)d_in[0];
  const float* qkv_w = (const float*)d_in[1];
  const float* out_w = (const float*)d_in[2];
  const float* base_c = (const float*)d_in[3];
  const float* deltas = (const float*)d_in[4];
  const float* log_sc = (const float*)d_in[5];
  const float* log_am = (const float*)d_in[6];
  const float* move_p = (const float*)d_in[7];
  const float* temp = (const float*)d_in[8];

  float* out = (float*)d_out;                    // B*T*D
  float* attn = out + (size_t)B_ * T_ * D_;      // B*T*T*H

  float* ws = (float*)d_ws;
  float* qkv = ws;                                          // 6,291,456 f
  float* qw = qkv + 6291456;                                // 524,288
  float* kw = qw + 524288;                                  // 524,288
  float* centers = kw + 524288;                             // 8,192
  float* inv_var = centers + 8192;                          // 128
  float* eff_amps = inv_var + 128;                          // 128
  float* inv_temp = eff_amps + 128;                         // 4
  float* m_g = inv_temp + 4;                                // 32,768
  float* is_g = m_g + 32768;                                // 32,768
  unsigned short* xh = (unsigned short*)(is_g + 32768);     // 2,097,152 us
  unsigned short* xl = xh + 2097152;                        // 2,097,152
  unsigned short* wh = xl + 2097152;                        // 786,432
  unsigned short* wl = wh + 786432;                         // 786,432
  unsigned short* owh = wl + 786432;                        // 262,144
  unsigned short* owl = owh + 262144;                       // 262,144
  unsigned short* oph = owl + 262144;                       // 2,097,152
  unsigned short* opl = oph + 2097152;                      // 2,097,152
  unsigned short* vth = opl + 2097152;                      // 2,097,152
  unsigned short* vtl = vth + 2097152;                      // 2,097,152

  k_params<<<32, 256, 0, stream>>>(base_c, deltas, log_sc, log_am, move_p, temp,
                                   centers, inv_var, eff_amps, inv_temp);
  k_split<<<2048, 256, 0, stream>>>(x, xh, xl, 2097152 / 4);
  k_split<<<768, 256, 0, stream>>>(qkv_w, wh, wl, 786432 / 4);
  k_split<<<256, 256, 0, stream>>>(out_w, owh, owl, 262144 / 4);

  dim3 g1(1536 / 64, 4096 / 128);   // 24 x 32 = 768 WGs
  gemm_mfma<64><<<g1, 256, 0, stream>>>(xh, xl, wh, wl, qkv, B_ * T_, 3 * D_, D_);

  k_gauss<<<(B_ * T_ * H_ * S_) / 256, 256, 0, stream>>>(qkv, centers, inv_var,
                                                         eff_amps, inv_temp, qw, kw);
  k_vtr<<<B_ * H_ * 16, 256, 0, stream>>>(qkv, vth, vtl);
  k_stats<<<B_ * H_ * (T_ / ITS), 256, 0, stream>>>(qw, kw, m_g, is_g);
  k_attnw<<<B_ * (T_ / ITW) * 4, 256, 0, stream>>>(qw, kw, m_g, is_g, attn);
  k_pv<<<B_ * H_ * (T_ / PVI), 256, 0, stream>>>(qw, kw, m_g, is_g, vth, vtl, oph, opl);

  dim3 g2(512 / 64, 4096 / 128);    // 8 x 32 = 256 WGs
  gemm_mfma<64><<<g2, 256, 0, stream>>>(oph, opl, owh, owl, out, B_ * T_, D_, D_);
}